// Round 4
// baseline (65.062 us; speedup 1.0000x reference)
//
#include <hip/hip_runtime.h>

#define BB 16
#define NN 100000
#define KK 8
#define BLOCK 256

#define DT_BYTES ((size_t)NN * 96)            // bf16 dT: 48 bf16 = 96B per vertex
#define GRID1 ((NN / 4 + 15) / 16)            // 1563 blocks, 64 vertices each
#define GRID2 ((NN * 2 + BLOCK - 1) / BLOCK)  // 782 blocks, 2 threads per vertex
#define SCALE (1.0f / ((float)BB * NN * 3))

// round-to-nearest-even f32 -> bf16, packed pair
__device__ __forceinline__ unsigned pk_bf16(float a, float b) {
    unsigned ua = __float_as_uint(a), ub = __float_as_uint(b);
    ua = (ua + 0x7FFFu + ((ua >> 16) & 1u)) >> 16;
    ub = (ub + 0x7FFFu + ((ub >> 16) & 1u)) >> 16;
    return ua | (ub << 16);
}

// a[0..7] += wv * unpack8(u)
__device__ __forceinline__ void fma8(float* a, uint4 u, float wv) {
    a[0] += wv * __uint_as_float(u.x << 16);
    a[1] += wv * __uint_as_float(u.x & 0xFFFF0000u);
    a[2] += wv * __uint_as_float(u.y << 16);
    a[3] += wv * __uint_as_float(u.y & 0xFFFF0000u);
    a[4] += wv * __uint_as_float(u.z << 16);
    a[5] += wv * __uint_as_float(u.z & 0xFFFF0000u);
    a[6] += wv * __uint_as_float(u.w << 16);
    a[7] += wv * __uint_as_float(u.w & 0xFFFF0000u);
}

// ---------- Kernel 1: coalesced diff + LDS transpose + bf16 pack ----------
// dT[n][b*3+c] (bf16, 48/row) = geom[b][n][c] - gtp[b][n][c]
__global__ __launch_bounds__(BLOCK) void diff_transpose_bf16_kernel(
    const float4* __restrict__ geom4,
    const float4* __restrict__ gtp4,
    uint4*        __restrict__ dT4,
    unsigned*     __restrict__ counter)
{
    __shared__ float tile[64][49];   // [vertex in block][b*3+c], +1 pad
    int tid = threadIdx.x;
    int b = tid >> 4;                // 0..15
    int q = tid & 15;                // n-quad within block
    int nbase = blockIdx.x * 64;
    int n0 = nbase + q * 4;

    if (blockIdx.x == 0 && tid == 0) *counter = 0u;   // reset for kernel 2

    if (n0 < NN) {
        int fi = (b * (NN * 3) + n0 * 3) >> 2;        // float4 index, coalesced
        float4 g0 = geom4[fi], g1 = geom4[fi + 1], g2 = geom4[fi + 2];
        float4 t0 = gtp4[fi],  t1 = gtp4[fi + 1],  t2 = gtp4[fi + 2];
        float d[12] = {g0.x - t0.x, g0.y - t0.y, g0.z - t0.z, g0.w - t0.w,
                       g1.x - t1.x, g1.y - t1.y, g1.z - t1.z, g1.w - t1.w,
                       g2.x - t2.x, g2.y - t2.y, g2.z - t2.z, g2.w - t2.w};
        #pragma unroll
        for (int e = 0; e < 12; ++e)
            tile[q * 4 + e / 3][b * 3 + e % 3] = d[e];
    }
    __syncthreads();

    // 64 rows x 6 uint4 per row = 384 fully-coalesced 16B stores
    #pragma unroll
    for (int i = 0; i < 2; ++i) {
        int t2 = i * BLOCK + tid;
        if (t2 < 384) {
            int r = t2 / 6, m = t2 - r * 6;
            int n = nbase + r;
            if (n < NN) {
                const float* row = &tile[r][m * 8];
                uint4 o;
                o.x = pk_bf16(row[0], row[1]);
                o.y = pk_bf16(row[2], row[3]);
                o.z = pk_bf16(row[4], row[5]);
                o.w = pk_bf16(row[6], row[7]);
                dT4[n * 6 + m] = o;
            }
        }
    }
}

// ---------- Kernel 2: gather + weighted sum + full reduce (last block) ----------
__global__ __launch_bounds__(BLOCK, 4) void lap_gather_reduce_kernel(
    const uint4* __restrict__ dv,
    const int*   __restrict__ idx,
    const float* __restrict__ w,
    float*       __restrict__ partial,
    unsigned*    __restrict__ counter,
    float*       __restrict__ out)
{
    int t = blockIdx.x * BLOCK + threadIdx.x;
    int n = t >> 1;
    int s = t & 1;                  // which half of the 96B row

    float ssq = 0.0f;
    if (n < NN) {
        int base = n * 6 + s;
        float a[24];
        #pragma unroll
        for (int i = 0; i < 24; ++i) a[i] = 0.0f;
        fma8(a,      dv[base],     1.0f);      // self term
        fma8(a + 8,  dv[base + 2], 1.0f);
        fma8(a + 16, dv[base + 4], 1.0f);

        const int4*   ip = reinterpret_cast<const int4*>(idx + (size_t)n * KK);
        const float4* wp = reinterpret_cast<const float4*>(w + (size_t)n * KK);
        int4   i0 = ip[0], i1 = ip[1];
        float4 w0 = wp[0], w1 = wp[1];
        int   js[KK] = {i0.x, i0.y, i0.z, i0.w, i1.x, i1.y, i1.z, i1.w};
        float wk[KK] = {w0.x, w0.y, w0.z, w0.w, w1.x, w1.y, w1.z, w1.w};

        #pragma unroll
        for (int k = 0; k < KK; ++k) {
            int jb = js[k] * 6 + s;
            uint4 v0 = dv[jb], v1 = dv[jb + 2], v2 = dv[jb + 4];
            float wv = wk[k];
            fma8(a,      v0, wv);
            fma8(a + 8,  v1, wv);
            fma8(a + 16, v2, wv);
        }
        #pragma unroll
        for (int i = 0; i < 24; ++i) ssq += a[i] * a[i];
    }

    #pragma unroll
    for (int off = 32; off > 0; off >>= 1)
        ssq += __shfl_down(ssq, off, 64);

    __shared__ float wsum[BLOCK / 64];
    __shared__ int   isLast;
    int lane = threadIdx.x & 63;
    int wid  = threadIdx.x >> 6;
    if (lane == 0) wsum[wid] = ssq;
    __syncthreads();

    if (threadIdx.x == 0) {
        float bs = wsum[0] + wsum[1] + wsum[2] + wsum[3];
        partial[blockIdx.x] = bs;
        __threadfence();
        unsigned old = atomicAdd(counter, 1u);
        isLast = (old == (unsigned)(GRID2 - 1));
    }
    __syncthreads();

    if (isLast) {
        __threadfence();   // acquire: see all blocks' partial[] stores
        float s2 = 0.0f;
        for (int i = threadIdx.x; i < GRID2; i += BLOCK)
            s2 += partial[i];
        #pragma unroll
        for (int off = 32; off > 0; off >>= 1)
            s2 += __shfl_down(s2, off, 64);
        __syncthreads();                 // wsum reuse hazard
        if (lane == 0) wsum[wid] = s2;
        __syncthreads();
        if (threadIdx.x == 0)
            out[0] = (wsum[0] + wsum[1] + wsum[2] + wsum[3]) * SCALE;
    }
}

extern "C" void kernel_launch(void* const* d_in, const int* in_sizes, int n_in,
                              void* d_out, int out_size, void* d_ws, size_t ws_size,
                              hipStream_t stream) {
    const float* geom = (const float*)d_in[0];
    const float* gtp  = (const float*)d_in[1];
    const int*   idx  = (const int*)d_in[2];
    const float* w    = (const float*)d_in[3];
    float* out = (float*)d_out;

    uint4*    dT4     = (uint4*)d_ws;
    unsigned* counter = (unsigned*)((char*)d_ws + DT_BYTES);
    float*    partial = (float*)((char*)d_ws + DT_BYTES + 64);

    diff_transpose_bf16_kernel<<<GRID1, BLOCK, 0, stream>>>(
        (const float4*)geom, (const float4*)gtp, dT4, counter);
    lap_gather_reduce_kernel<<<GRID2, BLOCK, 0, stream>>>(
        dT4, idx, w, partial, counter, out);
}